// Round 3
// baseline (1827.317 us; speedup 1.0000x reference)
//
#include <hip/hip_runtime.h>
#include <hip/hip_cooperative_groups.h>

namespace cg = cooperative_groups;

// Inputs fp32, OUTPUT fp32. N from in_sizes[3].
// ws layout: [0..255]   latent accumulator, 16 slots strided 16 floats (64 B apart)
//            [256..284] Tall (T(4), Tu(1), Tux(4), Tuxx(4), Tp(16) row-major)
//
// R3 changes vs 661us (R2 regression post-mortem):
//  - phaseA grid-stride accumulates per-thread partials in LDS (red[tid*17+o] += v,
//    2-way bank alias = free). R2's register acc[16] live across the MLP body caused
//    scratch spills (WRITE_SIZE 47.5MB, FETCH +22MB) -> 335us.
//  - ONE cooperative kernel: phaseA -> grid.sync -> tnet(block0) -> grid.sync -> phaseC.
//    Sum-of-dispatch vs dur_us showed ~40-50us of serialization per dependent launch
//    (R0 gap ~128us/3 kernels, R2 ~170us/4). Fallback to 4-kernel path if the
//    cooperative launch is refused.
#define TPB 256
#define NB_COOP 1024

typedef unsigned int uint;

struct CArgs {
  const float* w1[5]; const float* b1[5];
  const float* w2[5]; const float* b2[5];
  const float* w3[5]; const float* b3[5];
};

struct AllArgs {
  const float *means, *cov, *uu, *bnd, *su, *sux, *suxx, *spde;
  const float *lw1, *lb1, *lw2, *lb2, *lw3, *lb3;
  CArgs ta;
  const float *jw1, *jb1, *jw2, *jb2, *jw3, *jb3, *jw4, *jb4;
  float* ws; float* out; int n;
};

__device__ __forceinline__ float fast_tanh(float x) {
  // tanh(x) = sign(x) * (1 - e^{-2|x|}) / (1 + e^{-2|x|})
  const float ax = __builtin_fabsf(x);
  const float t  = __builtin_amdgcn_exp2f(-2.8853900817779268f * ax);  // e^{-2|x|}
  const float r  = (1.0f - t) * __builtin_amdgcn_rcpf(1.0f + t);
  return __builtin_copysignf(r, x);
}

// ---------- phase A per-row body: 17->16->32->16 MLP, accumulate into LDS ----------
__device__ __forceinline__ void phaseA_row(const AllArgs& A, int row, float* myred) {
  float x[17];
  { const float2 v = *(const float2*)(A.means + (size_t)row * 2); x[0] = v.x; x[1] = v.y; }
  { const float4 v = *(const float4*)(A.cov   + (size_t)row * 4); x[2] = v.x; x[3] = v.y; x[4] = v.z; x[5] = v.w; }
  x[6] = A.uu[row]; x[7] = A.bnd[row]; x[8] = A.su[row];
  { const float2 v = *(const float2*)(A.sux   + (size_t)row * 2); x[9]  = v.x; x[10] = v.y; }
  { const float2 v = *(const float2*)(A.suxx  + (size_t)row * 2); x[11] = v.x; x[12] = v.y; }
  { const float4 v = *(const float4*)(A.spde  + (size_t)row * 4); x[13] = v.x; x[14] = v.y; x[15] = v.z; x[16] = v.w; }

  float h1[16];
#pragma unroll
  for (int o = 0; o < 16; o++) {
    float s = A.lb1[o];
#pragma unroll
    for (int i = 0; i < 17; i++) s = fmaf(A.lw1[o * 17 + i], x[i], s);
    h1[o] = fast_tanh(s);
  }
  float h2[32];
#pragma unroll
  for (int o = 0; o < 32; o++) {
    float s = A.lb2[o];
#pragma unroll
    for (int i = 0; i < 16; i++) s = fmaf(A.lw2[o * 16 + i], h1[i], s);
    h2[o] = fast_tanh(s);
  }
#pragma unroll
  for (int o = 0; o < 16; o++) {
    float s = A.lb3[o];
#pragma unroll
    for (int i = 0; i < 32; i++) s = fmaf(A.lw3[o * 32 + i], h2[i], s);
    myred[o] += fast_tanh(s);  // LDS accumulate: keeps register peak low (no spills)
  }
}

// ---------- block reduce of red[256][17] -> 16 atomics ----------
__device__ __forceinline__ void phaseA_finish(int tid, float* red, float* red2,
                                              float* acc_out) {
  // stage 2: thread (g = tid>>4, c = tid&15) sums 16 rows of column c (2-way banks, free)
  const int c = tid & 15, g = tid >> 4;
  float part = 0.0f;
#pragma unroll
  for (int r = 0; r < 16; r++) part += red[(g * 16 + r) * 17 + c];
  red2[g * 17 + c] = part;
  __syncthreads();
  if (tid < 16) {
    float s = 0.0f;
#pragma unroll
    for (int g2 = 0; g2 < 16; g2++) s += red2[g2 * 17 + tid];
    atomicAdd(&acc_out[tid * 16], s);  // 64 B apart: one cache line per component
  }
}

// ---------- t-nets (one block's worth of threads): latent -> Tall[29] in ws ----------
__device__ __forceinline__ void tnet_compute(const AllArgs& A, int tid) {
  __shared__ float lat[16];
  __shared__ float H1s[5][48];
  __shared__ float H2s[5][32];
  float* tall = A.ws + 256;

  if (tid < 16) lat[tid] = A.ws[tid * 16] * (1.0f / (float)A.n);
  __syncthreads();
  if (tid < 240) {  // layer 1: 16 -> 48, tanh
    int net = tid / 48, o = tid % 48;
    float s = A.ta.b1[net][o];
#pragma unroll
    for (int i = 0; i < 16; i++) s = fmaf(A.ta.w1[net][o * 16 + i], lat[i], s);
    H1s[net][o] = fast_tanh(s);
  }
  __syncthreads();
  if (tid < 160) {  // layer 2: 48 -> 32, tanh
    int net = tid / 32, o = tid % 32;
    float s = A.ta.b2[net][o];
#pragma unroll
    for (int i = 0; i < 48; i++) s = fmaf(A.ta.w2[net][o * 48 + i], H1s[net][i], s);
    H2s[net][o] = fast_tanh(s);
  }
  __syncthreads();
  if (tid < 29) {   // layer 3: 32 -> dd*dd, + eye(dd)
    int net, o, dd;
    if      (tid < 4)  { net = 0; o = tid;      dd = 2; }
    else if (tid < 5)  { net = 1; o = tid - 4;  dd = 1; }
    else if (tid < 9)  { net = 2; o = tid - 5;  dd = 2; }
    else if (tid < 13) { net = 3; o = tid - 9;  dd = 2; }
    else               { net = 4; o = tid - 13; dd = 4; }
    float s = A.ta.b3[net][o];
#pragma unroll
    for (int i = 0; i < 32; i++) s = fmaf(A.ta.w3[net][o * 32 + i], H2s[net][i], s);
    if (o / dd == o % dd) s += 1.0f;
    tall[tid] = s;
  }
}

// ---------- phase C per-row body: t_params + j-net 15->16->32->48->16 ----------
__device__ __forceinline__ void phaseC_rowT(const AllArgs& A, const float* T, int row) {
  const float4 c4 = *(const float4*)(A.cov + (size_t)row * 4);
  float tp[15];
  // t_cov[i,k] = sum_j T[i,j] * cov[j,k]
  tp[0] = T[0] * c4.x + T[1] * c4.z;
  tp[1] = T[0] * c4.y + T[1] * c4.w;
  tp[2] = T[2] * c4.x + T[3] * c4.z;
  tp[3] = T[2] * c4.y + T[3] * c4.w;
  tp[4] = T[4] * A.uu[row];           // t_u
  tp[5] = A.bnd[row];                 // b passthrough
  tp[6] = T[4] * A.su[row];           // t_su
  { const float2 v = *(const float2*)(A.sux + (size_t)row * 2);
    tp[7] = T[5] * v.x + T[6] * v.y;
    tp[8] = T[7] * v.x + T[8] * v.y; }
  { const float2 v = *(const float2*)(A.suxx + (size_t)row * 2);
    tp[9]  = T[9]  * v.x + T[10] * v.y;
    tp[10] = T[11] * v.x + T[12] * v.y; }
  { const float4 v = *(const float4*)(A.spde + (size_t)row * 4);
#pragma unroll
    for (int a = 0; a < 4; a++)
      tp[11 + a] = T[13 + a * 4] * v.x + T[13 + a * 4 + 1] * v.y +
                   T[13 + a * 4 + 2] * v.z + T[13 + a * 4 + 3] * v.w; }

  float a1[16];
#pragma unroll
  for (int o = 0; o < 16; o++) {
    float s = A.jb1[o];
#pragma unroll
    for (int i = 0; i < 15; i++) s = fmaf(A.jw1[o * 15 + i], tp[i], s);
    a1[o] = fast_tanh(s);
  }
  float a2[32];
#pragma unroll
  for (int o = 0; o < 32; o++) {
    float s = A.jb2[o];
#pragma unroll
    for (int i = 0; i < 16; i++) s = fmaf(A.jw2[o * 16 + i], a1[i], s);
    a2[o] = fast_tanh(s);
  }
  // Streamed 32->48->16: never materialize g3[48]; peak live = a2[32]+a4[16].
  float a4[16];
#pragma unroll
  for (int j = 0; j < 16; j++) a4[j] = A.jb4[j];
#pragma unroll 8
  for (int o = 0; o < 48; o++) {
    float s = A.jb3[o];
#pragma unroll
    for (int i = 0; i < 32; i++) s = fmaf(A.jw3[o * 32 + i], a2[i], s);
    const float h = fast_tanh(s);
#pragma unroll
    for (int j = 0; j < 16; j++) a4[j] = fmaf(A.jw4[j * 48 + o], h, a4[j]);
  }
  float4* p = (float4*)(A.out + (size_t)row * 16);
  p[0] = make_float4(a4[0],  a4[1],  a4[2],  a4[3]);
  p[1] = make_float4(a4[4],  a4[5],  a4[6],  a4[7]);
  p[2] = make_float4(a4[8],  a4[9],  a4[10], a4[11]);
  p[3] = make_float4(a4[12], a4[13], a4[14], a4[15]);
}

// ---------- the fused cooperative kernel ----------
__global__ __launch_bounds__(TPB, 4) void fused_kernel(AllArgs A) {
  const int tid = threadIdx.x;
  cg::grid_group grid = cg::this_grid();
  __shared__ float red[TPB * 17];
  __shared__ float red2[16 * 17];

  // step 0: block 0 zeroes the 16 accumulator slots (replay-safe)
  if (blockIdx.x == 0 && tid < 16) A.ws[tid * 16] = 0.0f;
  grid.sync();

  // ---- phase A ----
  float* myred = &red[tid * 17];
#pragma unroll
  for (int o = 0; o < 16; o++) myred[o] = 0.0f;
  const int stride = gridDim.x * TPB;
  for (int row = blockIdx.x * TPB + tid; row < A.n; row += stride)
    phaseA_row(A, row, myred);
  __syncthreads();
  phaseA_finish(tid, red, red2, A.ws);
  grid.sync();

  // ---- t-nets in block 0 ----
  if (blockIdx.x == 0) { tnet_compute(A, tid); __threadfence(); }
  grid.sync();

  // ---- phase C ----
  float T[29];
  const float* tall = A.ws + 256;
#pragma unroll
  for (int i = 0; i < 29; i++) T[i] = tall[i];
  for (int row = blockIdx.x * TPB + tid; row < A.n; row += stride)
    phaseC_rowT(A, T, row);
}

// ---------- fallback path (non-cooperative), mirrors R1/R2 known-good ----------
__global__ __launch_bounds__(256) void zero_kernel(float* ws) {
  ws[threadIdx.x] = 0.0f;
}

__global__ __launch_bounds__(TPB, 4) void phaseA_fb(AllArgs A) {
  const int tid = threadIdx.x;
  __shared__ float red[TPB * 17];
  __shared__ float red2[16 * 17];
  float* myred = &red[tid * 17];
#pragma unroll
  for (int o = 0; o < 16; o++) myred[o] = 0.0f;
  const int row = blockIdx.x * TPB + tid;
  if (row < A.n) phaseA_row(A, row, myred);
  __syncthreads();
  phaseA_finish(tid, red, red2, A.ws);
}

__global__ __launch_bounds__(256) void tnet_kernel(AllArgs A) {
  tnet_compute(A, threadIdx.x);
}

__global__ __launch_bounds__(TPB, 4) void phaseC_fb(AllArgs A) {
  const int row = blockIdx.x * TPB + threadIdx.x;
  if (row >= A.n) return;
  float T[29];
  const float* tall = A.ws + 256;
#pragma unroll
  for (int i = 0; i < 29; i++) T[i] = tall[i];
  phaseC_rowT(A, T, row);
}

// ---------- launch ----------
extern "C" void kernel_launch(void* const* d_in, const int* in_sizes, int n_in,
                              void* d_out, int out_size, void* d_ws, size_t ws_size,
                              hipStream_t stream) {
  AllArgs A;
  A.means = (const float*)d_in[0]; A.cov  = (const float*)d_in[1];
  A.uu    = (const float*)d_in[2]; A.bnd  = (const float*)d_in[3];
  A.su    = (const float*)d_in[4]; A.sux  = (const float*)d_in[5];
  A.suxx  = (const float*)d_in[6]; A.spde = (const float*)d_in[7];
  A.lw1 = (const float*)d_in[8];  A.lb1 = (const float*)d_in[9];
  A.lw2 = (const float*)d_in[10]; A.lb2 = (const float*)d_in[11];
  A.lw3 = (const float*)d_in[12]; A.lb3 = (const float*)d_in[13];
  for (int k = 0; k < 5; k++) {
    int b = 14 + 6 * k;
    A.ta.w1[k] = (const float*)d_in[b];     A.ta.b1[k] = (const float*)d_in[b + 1];
    A.ta.w2[k] = (const float*)d_in[b + 2]; A.ta.b2[k] = (const float*)d_in[b + 3];
    A.ta.w3[k] = (const float*)d_in[b + 4]; A.ta.b3[k] = (const float*)d_in[b + 5];
  }
  A.jw1 = (const float*)d_in[44]; A.jb1 = (const float*)d_in[45];
  A.jw2 = (const float*)d_in[46]; A.jb2 = (const float*)d_in[47];
  A.jw3 = (const float*)d_in[48]; A.jb3 = (const float*)d_in[49];
  A.jw4 = (const float*)d_in[50]; A.jb4 = (const float*)d_in[51];
  A.ws = (float*)d_ws; A.out = (float*)d_out;
  A.n = in_sizes[3];  // boundaries: (N,)

  void* kargs[] = { (void*)&A };
  hipError_t err = hipLaunchCooperativeKernel((const void*)fused_kernel,
                                              dim3(NB_COOP), dim3(TPB),
                                              kargs, 0, stream);
  if (err != hipSuccess) {
    (void)hipGetLastError();  // clear sticky error; use 4-kernel fallback
    const int nblk = (A.n + TPB - 1) / TPB;
    zero_kernel<<<1, 256, 0, stream>>>(A.ws);
    phaseA_fb<<<nblk, TPB, 0, stream>>>(A);
    tnet_kernel<<<1, 256, 0, stream>>>(A);
    phaseC_fb<<<nblk, TPB, 0, stream>>>(A);
  }
}

// Round 4
// 437.148 us; speedup vs baseline: 4.1801x; 4.1801x over previous
//
#include <hip/hip_runtime.h>

// Inputs fp32, OUTPUT fp32. N from in_sizes[3].
// ws layout: [0..255]   latent accumulator, 16 slots strided 16 floats (64 B apart)
//            [256..284] Tall (T(4), Tu(1), Tux(4), Tuxx(4), Tp(16) row-major)
//
// R4: consolidation after R3 post-mortem.
//  - Fusion REFUTED: dur_us - sum(dispatch) ~= 185us whether 1 kernel or 4 ->
//    the gap is fixed harness overhead (input-restore), NOT launch serialization.
//  - R3 fused spilled (2.4 GB scratch traffic: per-kernel regalloc max + T[29]
//    VGPR array). Revert to 4 kernels.
//  - phaseA: one row/thread, 16 outputs written DIRECTLY to LDS red[tid*17+o]
//    (stride 17 -> <=2-way bank alias, free), then ONE two-stage block reduce +
//    16 atomics. Kills R1's 96 shuffles/row without R2's register-accum spills.
//  - phaseC: byte-identical to R2's known-good (scalar tall s_loads, VGPR 36,
//    no LDS, no barriers, ~150us, WRITE == output only).
#define TPB 256

typedef unsigned int uint;

__device__ __forceinline__ float fast_tanh(float x) {
  // tanh(x) = sign(x) * (1 - e^{-2|x|}) / (1 + e^{-2|x|})
  const float ax = __builtin_fabsf(x);
  const float t  = __builtin_amdgcn_exp2f(-2.8853900817779268f * ax);  // e^{-2|x|}
  const float r  = (1.0f - t) * __builtin_amdgcn_rcpf(1.0f + t);
  return __builtin_copysignf(r, x);
}

// ---------- zero latent accumulator ----------
__global__ __launch_bounds__(256) void zero_kernel(float* ws) {
  ws[threadIdx.x] = 0.0f;
}

// ---------- phase A: one row/thread MLP 17->16->32->16, LDS write + block reduce ----------
__global__ __launch_bounds__(TPB, 4) void phaseA_kernel(
    const float* __restrict__ means, const float* __restrict__ cov,
    const float* __restrict__ uu,    const float* __restrict__ bnd,
    const float* __restrict__ su,    const float* __restrict__ sux,
    const float* __restrict__ suxx,  const float* __restrict__ spde,
    const float* __restrict__ lw1, const float* __restrict__ lb1,
    const float* __restrict__ lw2, const float* __restrict__ lb2,
    const float* __restrict__ lw3, const float* __restrict__ lb3,
    float* __restrict__ acc_out, int n) {
  const int tid = threadIdx.x;
  const int row = blockIdx.x * TPB + tid;
  const bool valid = row < n;
  const int r = valid ? row : 0;
  __shared__ float red[TPB * 17];
  __shared__ float red2[16 * 17];

  // params = concat([means(2), cov(4), u(1), b(1), su(1), sux(2), suxx(2), spde(4)])
  float x[17];
  { const float2 v = *(const float2*)(means + (size_t)r * 2); x[0] = v.x; x[1] = v.y; }
  { const float4 v = *(const float4*)(cov   + (size_t)r * 4); x[2] = v.x; x[3] = v.y; x[4] = v.z; x[5] = v.w; }
  x[6] = uu[r]; x[7] = bnd[r]; x[8] = su[r];
  { const float2 v = *(const float2*)(sux   + (size_t)r * 2); x[9]  = v.x; x[10] = v.y; }
  { const float2 v = *(const float2*)(suxx  + (size_t)r * 2); x[11] = v.x; x[12] = v.y; }
  { const float4 v = *(const float4*)(spde  + (size_t)r * 4); x[13] = v.x; x[14] = v.y; x[15] = v.z; x[16] = v.w; }

  float h1[16];
#pragma unroll
  for (int o = 0; o < 16; o++) {
    float s = lb1[o];
#pragma unroll
    for (int i = 0; i < 17; i++) s = fmaf(lw1[o * 17 + i], x[i], s);
    h1[o] = fast_tanh(s);
  }
  float h2[32];
#pragma unroll
  for (int o = 0; o < 32; o++) {
    float s = lb2[o];
#pragma unroll
    for (int i = 0; i < 16; i++) s = fmaf(lw2[o * 16 + i], h1[i], s);
    h2[o] = fast_tanh(s);
  }
  // layer 3 written straight to LDS (stride 17: <=2-way bank alias = free)
#pragma unroll
  for (int o = 0; o < 16; o++) {
    float s = lb3[o];
#pragma unroll
    for (int i = 0; i < 32; i++) s = fmaf(lw3[o * 32 + i], h2[i], s);
    red[tid * 17 + o] = valid ? fast_tanh(s) : 0.0f;
  }
  __syncthreads();

  // stage 2: thread (g = tid>>4, c = tid&15) sums 16 rows of column c
  {
    const int c = tid & 15, g = tid >> 4;
    float part = 0.0f;
#pragma unroll
    for (int rr = 0; rr < 16; rr++) part += red[(g * 16 + rr) * 17 + c];
    red2[g * 17 + c] = part;
  }
  __syncthreads();
  if (tid < 16) {
    float s = 0.0f;
#pragma unroll
    for (int g = 0; g < 16; g++) s += red2[g * 17 + tid];
    atomicAdd(&acc_out[tid * 16], s);  // 64 B apart: one cache line per component
  }
}

// ---------- t-nets: single block, writes Tall[29] to ws ----------
struct CArgs {
  const float* w1[5]; const float* b1[5];
  const float* w2[5]; const float* b2[5];
  const float* w3[5]; const float* b3[5];
};

__global__ __launch_bounds__(256) void tnet_kernel(
    CArgs ta, const float* __restrict__ ws_acc, float* __restrict__ tall, int n) {
  const int tid = threadIdx.x;
  __shared__ float lat[16];
  __shared__ float H1s[5][48];
  __shared__ float H2s[5][32];

  if (tid < 16) lat[tid] = ws_acc[tid * 16] * (1.0f / (float)n);
  __syncthreads();
  if (tid < 240) {  // _tnet layer 1: 16 -> 48, tanh
    int net = tid / 48, o = tid % 48;
    float s = ta.b1[net][o];
#pragma unroll
    for (int i = 0; i < 16; i++) s = fmaf(ta.w1[net][o * 16 + i], lat[i], s);
    H1s[net][o] = fast_tanh(s);
  }
  __syncthreads();
  if (tid < 160) {  // _tnet layer 2: 48 -> 32, tanh
    int net = tid / 32, o = tid % 32;
    float s = ta.b2[net][o];
#pragma unroll
    for (int i = 0; i < 48; i++) s = fmaf(ta.w2[net][o * 48 + i], H1s[net][i], s);
    H2s[net][o] = fast_tanh(s);
  }
  __syncthreads();
  if (tid < 29) {   // _tnet layer 3: 32 -> dd*dd, + eye(dd)
    int net, o, dd;
    if      (tid < 4)  { net = 0; o = tid;      dd = 2; }
    else if (tid < 5)  { net = 1; o = tid - 4;  dd = 1; }
    else if (tid < 9)  { net = 2; o = tid - 5;  dd = 2; }
    else if (tid < 13) { net = 3; o = tid - 9;  dd = 2; }
    else               { net = 4; o = tid - 13; dd = 4; }
    float s = ta.b3[net][o];
#pragma unroll
    for (int i = 0; i < 32; i++) s = fmaf(ta.w3[net][o * 32 + i], H2s[net][i], s);
    if (o / dd == o % dd) s += 1.0f;
    tall[tid] = s;
  }
}

// ---------- phase C: pure streaming per-row transform + j-net (no LDS, no barriers) ----------
__global__ __launch_bounds__(TPB, 4) void phaseC_kernel(
    const float* __restrict__ tall,
    const float* __restrict__ cov,  const float* __restrict__ uu,
    const float* __restrict__ bnd,  const float* __restrict__ su,
    const float* __restrict__ sux,  const float* __restrict__ suxx,
    const float* __restrict__ spde,
    const float* __restrict__ jw1,  const float* __restrict__ jb1,
    const float* __restrict__ jw2,  const float* __restrict__ jb2,
    const float* __restrict__ jw3,  const float* __restrict__ jb3,
    const float* __restrict__ jw4,  const float* __restrict__ jb4,
    float* __restrict__ out, int n) {
  const int row = blockIdx.x * TPB + threadIdx.x;
  if (row >= n) return;

  // Tall[29]: wave-uniform -> scalar loads through K$ (do NOT copy into a VGPR array)
  // T(4)@0, Tu(1)@4, Tux(4)@5, Tuxx(4)@9, Tp(16)@13 (row-major dd x dd)

  // ---- literal t_params ----
  const float4 c4 = *(const float4*)(cov + (size_t)row * 4);
  float tp[15];
  // t_cov[i,k] = sum_j T[i,j] * cov[j,k]
  tp[0] = tall[0] * c4.x + tall[1] * c4.z;
  tp[1] = tall[0] * c4.y + tall[1] * c4.w;
  tp[2] = tall[2] * c4.x + tall[3] * c4.z;
  tp[3] = tall[2] * c4.y + tall[3] * c4.w;
  tp[4] = tall[4] * uu[row];          // t_u
  tp[5] = bnd[row];                   // b passthrough
  tp[6] = tall[4] * su[row];          // t_su
  { const float2 v = *(const float2*)(sux + (size_t)row * 2);
    tp[7] = tall[5] * v.x + tall[6] * v.y;
    tp[8] = tall[7] * v.x + tall[8] * v.y; }
  { const float2 v = *(const float2*)(suxx + (size_t)row * 2);
    tp[9]  = tall[9]  * v.x + tall[10] * v.y;
    tp[10] = tall[11] * v.x + tall[12] * v.y; }
  { const float4 v = *(const float4*)(spde + (size_t)row * 4);
#pragma unroll
    for (int a = 0; a < 4; a++)
      tp[11 + a] = tall[13 + a * 4] * v.x + tall[13 + a * 4 + 1] * v.y +
                   tall[13 + a * 4 + 2] * v.z + tall[13 + a * 4 + 3] * v.w; }

  // ---- literal j-net: 15 -> 16 -> 32 -> 48 -> 16 ----
  float a1[16];
#pragma unroll
  for (int o = 0; o < 16; o++) {
    float s = jb1[o];
#pragma unroll
    for (int i = 0; i < 15; i++) s = fmaf(jw1[o * 15 + i], tp[i], s);
    a1[o] = fast_tanh(s);
  }
  float a2[32];
#pragma unroll
  for (int o = 0; o < 32; o++) {
    float s = jb2[o];
#pragma unroll
    for (int i = 0; i < 16; i++) s = fmaf(jw2[o * 16 + i], a1[i], s);
    a2[o] = fast_tanh(s);
  }
  // Streamed 32->48->16: never materialize g3[48]; peak live = a2[32]+a4[16].
  float a4[16];
#pragma unroll
  for (int j = 0; j < 16; j++) a4[j] = jb4[j];
#pragma unroll 8
  for (int o = 0; o < 48; o++) {
    float s = jb3[o];
#pragma unroll
    for (int i = 0; i < 32; i++) s = fmaf(jw3[o * 32 + i], a2[i], s);
    const float h = fast_tanh(s);
#pragma unroll
    for (int j = 0; j < 16; j++) a4[j] = fmaf(jw4[j * 48 + o], h, a4[j]);
  }
  float4* p = (float4*)(out + (size_t)row * 16);
  p[0] = make_float4(a4[0],  a4[1],  a4[2],  a4[3]);
  p[1] = make_float4(a4[4],  a4[5],  a4[6],  a4[7]);
  p[2] = make_float4(a4[8],  a4[9],  a4[10], a4[11]);
  p[3] = make_float4(a4[12], a4[13], a4[14], a4[15]);
}

// ---------- launch ----------
extern "C" void kernel_launch(void* const* d_in, const int* in_sizes, int n_in,
                              void* d_out, int out_size, void* d_ws, size_t ws_size,
                              hipStream_t stream) {
  float* ws = (float*)d_ws;
  const int n = in_sizes[3];              // boundaries: (N,)
  const int nblk = (n + TPB - 1) / TPB;

  zero_kernel<<<1, 256, 0, stream>>>(ws);

  phaseA_kernel<<<nblk, TPB, 0, stream>>>(
      (const float*)d_in[0], (const float*)d_in[1], (const float*)d_in[2],
      (const float*)d_in[3], (const float*)d_in[4], (const float*)d_in[5],
      (const float*)d_in[6], (const float*)d_in[7],
      (const float*)d_in[8], (const float*)d_in[9], (const float*)d_in[10],
      (const float*)d_in[11], (const float*)d_in[12], (const float*)d_in[13],
      ws, n);

  CArgs ca;
  for (int k = 0; k < 5; k++) {
    int b = 14 + 6 * k;
    ca.w1[k] = (const float*)d_in[b];     ca.b1[k] = (const float*)d_in[b + 1];
    ca.w2[k] = (const float*)d_in[b + 2]; ca.b2[k] = (const float*)d_in[b + 3];
    ca.w3[k] = (const float*)d_in[b + 4]; ca.b3[k] = (const float*)d_in[b + 5];
  }

  tnet_kernel<<<1, 256, 0, stream>>>(ca, ws, ws + 256, n);

  phaseC_kernel<<<nblk, TPB, 0, stream>>>(
      ws + 256,
      (const float*)d_in[1], (const float*)d_in[2], (const float*)d_in[3],
      (const float*)d_in[4], (const float*)d_in[5], (const float*)d_in[6],
      (const float*)d_in[7],
      (const float*)d_in[44], (const float*)d_in[45],
      (const float*)d_in[46], (const float*)d_in[47],
      (const float*)d_in[48], (const float*)d_in[49],
      (const float*)d_in[50], (const float*)d_in[51],
      (float*)d_out, n);
}

// Round 5
// 402.299 us; speedup vs baseline: 4.5422x; 1.0866x over previous
//
#include <hip/hip_runtime.h>

// Inputs fp32, OUTPUT fp32. N from in_sizes[3].
// ws layout: [0..255]   latent accumulator, 16 slots strided 16 floats (64 B apart)
//            [256..284] Tall (T(4), Tu(1), Tux(4), Tuxx(4), Tp(16) row-major)
//
// R5: packed-fp32 (v_pk_fma_f32) restructure of the dot products.
//  - MI355X plain v_fma_f32 tops at ~103 TF (m07); 157.3 TF spec needs packed fp32.
//    Serial fmaf chains can't pack -> rewrite every even-K dot as a float2 two-lane
//    accumulator (__builtin_elementwise_fma on ext_vector float2), horizontal add at
//    the end. Weight pairs are memory-adjacent (even-K rows, 8B aligned -> s_load x2).
//    Activations live in v2f register arrays, ALL indices compile-time (no scratch).
//  - Coverage: phaseC L2/L3/L4 (2816/3106 FMAs; L4 packed over o-pairs), phaseA L2/L3
//    (1024/1296). Odd-K first layers (15/17) stay scalar fmaf (SMEM pair alignment).
//  - fast_tanh v2: tanh(x) = 1 - 2*rcp(1 + exp2(2log2e*x)): 3 VALU + 2 trans, no
//    abs/copysign, exact saturation at +-inf, abs err < 2^-22.
//  - Tripwire: phaseC WRITE_SIZE must stay 62500 KB; if it balloons, L4 v2f
//    accumulators (a2v+a4v ~75 live VGPRs) spilled -> revert L4 packing next round.
#define TPB 256

typedef unsigned int uint;
typedef float v2f __attribute__((ext_vector_type(2)));

__device__ __forceinline__ v2f pk_fma(v2f a, v2f b, v2f c) {
  return __builtin_elementwise_fma(a, b, c);
}

__device__ __forceinline__ float fast_tanh(float x) {
  // tanh(x) = 1 - 2/(1 + e^{2x}); e^{2x} = exp2(2*log2(e)*x)
  const float t = __builtin_amdgcn_exp2f(2.8853900817779268f * x);
  const float r = __builtin_amdgcn_rcpf(1.0f + t);
  return fmaf(-2.0f, r, 1.0f);
}

// ---------- zero latent accumulator ----------
__global__ __launch_bounds__(256) void zero_kernel(float* ws) {
  ws[threadIdx.x] = 0.0f;
}

// ---------- phase A: one row/thread MLP 17->16->32->16, LDS write + block reduce ----------
__global__ __launch_bounds__(TPB, 4) void phaseA_kernel(
    const float* __restrict__ means, const float* __restrict__ cov,
    const float* __restrict__ uu,    const float* __restrict__ bnd,
    const float* __restrict__ su,    const float* __restrict__ sux,
    const float* __restrict__ suxx,  const float* __restrict__ spde,
    const float* __restrict__ lw1, const float* __restrict__ lb1,
    const float* __restrict__ lw2, const float* __restrict__ lb2,
    const float* __restrict__ lw3, const float* __restrict__ lb3,
    float* __restrict__ acc_out, int n) {
  const int tid = threadIdx.x;
  const int row = blockIdx.x * TPB + tid;
  const bool valid = row < n;
  const int r = valid ? row : 0;
  __shared__ float red[TPB * 17];
  __shared__ float red2[16 * 17];

  // params = concat([means(2), cov(4), u(1), b(1), su(1), sux(2), suxx(2), spde(4)])
  float x[17];
  { const float2 v = *(const float2*)(means + (size_t)r * 2); x[0] = v.x; x[1] = v.y; }
  { const float4 v = *(const float4*)(cov   + (size_t)r * 4); x[2] = v.x; x[3] = v.y; x[4] = v.z; x[5] = v.w; }
  x[6] = uu[r]; x[7] = bnd[r]; x[8] = su[r];
  { const float2 v = *(const float2*)(sux   + (size_t)r * 2); x[9]  = v.x; x[10] = v.y; }
  { const float2 v = *(const float2*)(suxx  + (size_t)r * 2); x[11] = v.x; x[12] = v.y; }
  { const float4 v = *(const float4*)(spde  + (size_t)r * 4); x[13] = v.x; x[14] = v.y; x[15] = v.z; x[16] = v.w; }

  // L1: 17 -> 16 (K odd: scalar fmaf), results into v2f pairs
  v2f h1v[8];
#pragma unroll
  for (int o = 0; o < 16; o++) {
    float s = lb1[o];
#pragma unroll
    for (int i = 0; i < 17; i++) s = fmaf(lw1[o * 17 + i], x[i], s);
    h1v[o >> 1][o & 1] = fast_tanh(s);
  }
  // L2: 16 -> 32, packed (8 pk_fma per output)
  v2f h2v[16];
#pragma unroll
  for (int o = 0; o < 32; o++) {
    v2f acc = {lb2[o], 0.0f};
    const v2f* w2 = (const v2f*)(lw2 + o * 16);
#pragma unroll
    for (int m = 0; m < 8; m++) acc = pk_fma(w2[m], h1v[m], acc);
    h2v[o >> 1][o & 1] = fast_tanh(acc.x + acc.y);
  }
  // L3: 32 -> 16, packed, written straight to LDS (stride 17: <=2-way bank alias)
#pragma unroll
  for (int o = 0; o < 16; o++) {
    v2f acc = {lb3[o], 0.0f};
    const v2f* w2 = (const v2f*)(lw3 + o * 32);
#pragma unroll
    for (int m = 0; m < 16; m++) acc = pk_fma(w2[m], h2v[m], acc);
    red[tid * 17 + o] = valid ? fast_tanh(acc.x + acc.y) : 0.0f;
  }
  __syncthreads();

  // stage 2: thread (g = tid>>4, c = tid&15) sums 16 rows of column c
  {
    const int c = tid & 15, g = tid >> 4;
    float part = 0.0f;
#pragma unroll
    for (int rr = 0; rr < 16; rr++) part += red[(g * 16 + rr) * 17 + c];
    red2[g * 17 + c] = part;
  }
  __syncthreads();
  if (tid < 16) {
    float s = 0.0f;
#pragma unroll
    for (int g = 0; g < 16; g++) s += red2[g * 17 + tid];
    atomicAdd(&acc_out[tid * 16], s);  // 64 B apart: one cache line per component
  }
}

// ---------- t-nets: single block, writes Tall[29] to ws ----------
struct CArgs {
  const float* w1[5]; const float* b1[5];
  const float* w2[5]; const float* b2[5];
  const float* w3[5]; const float* b3[5];
};

__global__ __launch_bounds__(256) void tnet_kernel(
    CArgs ta, const float* __restrict__ ws_acc, float* __restrict__ tall, int n) {
  const int tid = threadIdx.x;
  __shared__ float lat[16];
  __shared__ float H1s[5][48];
  __shared__ float H2s[5][32];

  if (tid < 16) lat[tid] = ws_acc[tid * 16] * (1.0f / (float)n);
  __syncthreads();
  if (tid < 240) {  // _tnet layer 1: 16 -> 48, tanh
    int net = tid / 48, o = tid % 48;
    float s = ta.b1[net][o];
#pragma unroll
    for (int i = 0; i < 16; i++) s = fmaf(ta.w1[net][o * 16 + i], lat[i], s);
    H1s[net][o] = fast_tanh(s);
  }
  __syncthreads();
  if (tid < 160) {  // _tnet layer 2: 48 -> 32, tanh
    int net = tid / 32, o = tid % 32;
    float s = ta.b2[net][o];
#pragma unroll
    for (int i = 0; i < 48; i++) s = fmaf(ta.w2[net][o * 48 + i], H1s[net][i], s);
    H2s[net][o] = fast_tanh(s);
  }
  __syncthreads();
  if (tid < 29) {   // _tnet layer 3: 32 -> dd*dd, + eye(dd)
    int net, o, dd;
    if      (tid < 4)  { net = 0; o = tid;      dd = 2; }
    else if (tid < 5)  { net = 1; o = tid - 4;  dd = 1; }
    else if (tid < 9)  { net = 2; o = tid - 5;  dd = 2; }
    else if (tid < 13) { net = 3; o = tid - 9;  dd = 2; }
    else               { net = 4; o = tid - 13; dd = 4; }
    float s = ta.b3[net][o];
#pragma unroll
    for (int i = 0; i < 32; i++) s = fmaf(ta.w3[net][o * 32 + i], H2s[net][i], s);
    if (o / dd == o % dd) s += 1.0f;
    tall[tid] = s;
  }
}

// ---------- phase C: pure streaming per-row transform + j-net (no LDS, no barriers) ----------
__global__ __launch_bounds__(TPB, 4) void phaseC_kernel(
    const float* __restrict__ tall,
    const float* __restrict__ cov,  const float* __restrict__ uu,
    const float* __restrict__ bnd,  const float* __restrict__ su,
    const float* __restrict__ sux,  const float* __restrict__ suxx,
    const float* __restrict__ spde,
    const float* __restrict__ jw1,  const float* __restrict__ jb1,
    const float* __restrict__ jw2,  const float* __restrict__ jb2,
    const float* __restrict__ jw3,  const float* __restrict__ jb3,
    const float* __restrict__ jw4,  const float* __restrict__ jb4,
    float* __restrict__ out, int n) {
  const int row = blockIdx.x * TPB + threadIdx.x;
  if (row >= n) return;

  // Tall[29]: wave-uniform -> scalar loads through K$ (do NOT copy into a VGPR array)
  // T(4)@0, Tu(1)@4, Tux(4)@5, Tuxx(4)@9, Tp(16)@13 (row-major dd x dd)

  // ---- literal t_params ----
  const float4 c4 = *(const float4*)(cov + (size_t)row * 4);
  float tp[15];
  // t_cov[i,k] = sum_j T[i,j] * cov[j,k]
  tp[0] = tall[0] * c4.x + tall[1] * c4.z;
  tp[1] = tall[0] * c4.y + tall[1] * c4.w;
  tp[2] = tall[2] * c4.x + tall[3] * c4.z;
  tp[3] = tall[2] * c4.y + tall[3] * c4.w;
  tp[4] = tall[4] * uu[row];          // t_u
  tp[5] = bnd[row];                   // b passthrough
  tp[6] = tall[4] * su[row];          // t_su
  { const float2 v = *(const float2*)(sux + (size_t)row * 2);
    tp[7] = tall[5] * v.x + tall[6] * v.y;
    tp[8] = tall[7] * v.x + tall[8] * v.y; }
  { const float2 v = *(const float2*)(suxx + (size_t)row * 2);
    tp[9]  = tall[9]  * v.x + tall[10] * v.y;
    tp[10] = tall[11] * v.x + tall[12] * v.y; }
  { const float4 v = *(const float4*)(spde + (size_t)row * 4);
#pragma unroll
    for (int a = 0; a < 4; a++)
      tp[11 + a] = tall[13 + a * 4] * v.x + tall[13 + a * 4 + 1] * v.y +
                   tall[13 + a * 4 + 2] * v.z + tall[13 + a * 4 + 3] * v.w; }

  // ---- j-net: 15 -> 16 -> 32 -> 48 -> 16 ----
  // L1 (K=15 odd: scalar fmaf), results into v2f pairs
  v2f a1v[8];
#pragma unroll
  for (int o = 0; o < 16; o++) {
    float s = jb1[o];
#pragma unroll
    for (int i = 0; i < 15; i++) s = fmaf(jw1[o * 15 + i], tp[i], s);
    a1v[o >> 1][o & 1] = fast_tanh(s);
  }
  // L2: 16 -> 32, packed
  v2f a2v[16];
#pragma unroll
  for (int o = 0; o < 32; o++) {
    v2f acc = {jb2[o], 0.0f};
    const v2f* w2 = (const v2f*)(jw2 + o * 16);
#pragma unroll
    for (int m = 0; m < 8; m++) acc = pk_fma(w2[m], a1v[m], acc);
    a2v[o >> 1][o & 1] = fast_tanh(acc.x + acc.y);
  }
  // L3+L4 streamed in o-PAIRS: dot(32) packed for o and o+1, tanh both, then
  // a4v[j] += {w4[j][o], w4[j][o+1]} * {h0, h1} (adjacent weights -> packed).
  // Never materializes g3[48]; peak live = a2v(32) + a4v(32) + 2 acc pairs.
  v2f a4v[16];
#pragma unroll
  for (int j = 0; j < 16; j++) { v2f t = {jb4[j], 0.0f}; a4v[j] = t; }
#pragma unroll 4
  for (int op = 0; op < 24; op++) {
    const int o0 = op * 2;
    v2f acc0 = {jb3[o0], 0.0f};
    v2f acc1 = {jb3[o0 + 1], 0.0f};
    const v2f* w30 = (const v2f*)(jw3 + o0 * 32);
    const v2f* w31 = (const v2f*)(jw3 + (o0 + 1) * 32);
#pragma unroll
    for (int m = 0; m < 16; m++) {
      acc0 = pk_fma(w30[m], a2v[m], acc0);
      acc1 = pk_fma(w31[m], a2v[m], acc1);
    }
    v2f h;
    h.x = fast_tanh(acc0.x + acc0.y);
    h.y = fast_tanh(acc1.x + acc1.y);
#pragma unroll
    for (int j = 0; j < 16; j++)
      a4v[j] = pk_fma(*(const v2f*)(jw4 + j * 48 + o0), h, a4v[j]);
  }
  float4* p = (float4*)(out + (size_t)row * 16);
  p[0] = make_float4(a4v[0].x + a4v[0].y,   a4v[1].x + a4v[1].y,
                     a4v[2].x + a4v[2].y,   a4v[3].x + a4v[3].y);
  p[1] = make_float4(a4v[4].x + a4v[4].y,   a4v[5].x + a4v[5].y,
                     a4v[6].x + a4v[6].y,   a4v[7].x + a4v[7].y);
  p[2] = make_float4(a4v[8].x + a4v[8].y,   a4v[9].x + a4v[9].y,
                     a4v[10].x + a4v[10].y, a4v[11].x + a4v[11].y);
  p[3] = make_float4(a4v[12].x + a4v[12].y, a4v[13].x + a4v[13].y,
                     a4v[14].x + a4v[14].y, a4v[15].x + a4v[15].y);
}

// ---------- launch ----------
extern "C" void kernel_launch(void* const* d_in, const int* in_sizes, int n_in,
                              void* d_out, int out_size, void* d_ws, size_t ws_size,
                              hipStream_t stream) {
  float* ws = (float*)d_ws;
  const int n = in_sizes[3];              // boundaries: (N,)
  const int nblk = (n + TPB - 1) / TPB;

  zero_kernel<<<1, 256, 0, stream>>>(ws);

  phaseA_kernel<<<nblk, TPB, 0, stream>>>(
      (const float*)d_in[0], (const float*)d_in[1], (const float*)d_in[2],
      (const float*)d_in[3], (const float*)d_in[4], (const float*)d_in[5],
      (const float*)d_in[6], (const float*)d_in[7],
      (const float*)d_in[8], (const float*)d_in[9], (const float*)d_in[10],
      (const float*)d_in[11], (const float*)d_in[12], (const float*)d_in[13],
      ws, n);

  CArgs ca;
  for (int k = 0; k < 5; k++) {
    int b = 14 + 6 * k;
    ca.w1[k] = (const float*)d_in[b];     ca.b1[k] = (const float*)d_in[b + 1];
    ca.w2[k] = (const float*)d_in[b + 2]; ca.b2[k] = (const float*)d_in[b + 3];
    ca.w3[k] = (const float*)d_in[b + 4]; ca.b3[k] = (const float*)d_in[b + 5];
  }

  tnet_kernel<<<1, 256, 0, stream>>>(ca, ws, ws + 256, n);

  phaseC_kernel<<<nblk, TPB, 0, stream>>>(
      ws + 256,
      (const float*)d_in[1], (const float*)d_in[2], (const float*)d_in[3],
      (const float*)d_in[4], (const float*)d_in[5], (const float*)d_in[6],
      (const float*)d_in[7],
      (const float*)d_in[44], (const float*)d_in[45],
      (const float*)d_in[46], (const float*)d_in[47],
      (const float*)d_in[48], (const float*)d_in[49],
      (const float*)d_in[50], (const float*)d_in[51],
      (float*)d_out, n);
}

// Round 6
// 353.676 us; speedup vs baseline: 5.1666x; 1.1375x over previous
//
#include <hip/hip_runtime.h>

// Inputs fp32, OUTPUT fp32. N from in_sizes[3].
// ws layout: [0..255]   latent accumulator, 16 slots strided 16 floats (64 B apart)
//            [256..284] Tall (T(4), Tu(1), Tux(4), Tuxx(4), Tp(16) row-major)
//
// R6: phaseA 2 rows/thread.
//  - R5 counters: phaseA 130us @ VALUBusy 26% -> ~75% stalled; VALU work is only
//    ~34us. Diagnosis: wave-uniform weight s_load stream (5.4 KB re-walked per row,
//    96 SGPRs -> few batches in flight) has too little FMA per load to hide lgkm
//    latency. Fix: each thread computes TWO rows; every weight s-pair feeds two
//    independent pk_fma chains (2x work per scalar load, 2x ILP). K-packed codegen
//    (adjacent weight pairs -> s-pair operand of v_pk_fma_f32) kept EXACTLY as R5
//    proved out. Register audit: peak live ~85 < 128 cap -> no spills.
//  - Tripwire: phaseA WRITE_SIZE must stay ~1-2 MB; balloon = spill = revert.
//  - phaseC byte-identical to R5 (won 155 -> <=129; re-measure before touching).
#define TPB 256

typedef unsigned int uint;
typedef float v2f __attribute__((ext_vector_type(2)));

__device__ __forceinline__ v2f pk_fma(v2f a, v2f b, v2f c) {
  return __builtin_elementwise_fma(a, b, c);
}

__device__ __forceinline__ float fast_tanh(float x) {
  // tanh(x) = 1 - 2/(1 + e^{2x}); e^{2x} = exp2(2*log2(e)*x)
  const float t = __builtin_amdgcn_exp2f(2.8853900817779268f * x);
  const float r = __builtin_amdgcn_rcpf(1.0f + t);
  return fmaf(-2.0f, r, 1.0f);
}

// ---------- zero latent accumulator ----------
__global__ __launch_bounds__(256) void zero_kernel(float* ws) {
  ws[threadIdx.x] = 0.0f;
}

// ---------- phase A: TWO rows/thread MLP 17->16->32->16, LDS write + block reduce ----------
__global__ __launch_bounds__(TPB, 4) void phaseA_kernel(
    const float* __restrict__ means, const float* __restrict__ cov,
    const float* __restrict__ uu,    const float* __restrict__ bnd,
    const float* __restrict__ su,    const float* __restrict__ sux,
    const float* __restrict__ suxx,  const float* __restrict__ spde,
    const float* __restrict__ lw1, const float* __restrict__ lb1,
    const float* __restrict__ lw2, const float* __restrict__ lb2,
    const float* __restrict__ lw3, const float* __restrict__ lb3,
    float* __restrict__ acc_out, int n) {
  const int tid = threadIdx.x;
  const int r0i = blockIdx.x * (TPB * 2) + tid;
  const int r1i = r0i + TPB;
  const bool v0 = r0i < n, v1 = r1i < n;
  const int r0 = v0 ? r0i : 0, r1 = v1 ? r1i : 0;
  __shared__ float red[TPB * 17];
  __shared__ float red2[16 * 17];

  // params = concat([means(2), cov(4), u(1), b(1), su(1), sux(2), suxx(2), spde(4)])
  auto load17 = [&](int r, float* x) {
    { const float2 v = *(const float2*)(means + (size_t)r * 2); x[0] = v.x; x[1] = v.y; }
    { const float4 v = *(const float4*)(cov   + (size_t)r * 4); x[2] = v.x; x[3] = v.y; x[4] = v.z; x[5] = v.w; }
    x[6] = uu[r]; x[7] = bnd[r]; x[8] = su[r];
    { const float2 v = *(const float2*)(sux   + (size_t)r * 2); x[9]  = v.x; x[10] = v.y; }
    { const float2 v = *(const float2*)(suxx  + (size_t)r * 2); x[11] = v.x; x[12] = v.y; }
    { const float4 v = *(const float4*)(spde  + (size_t)r * 4); x[13] = v.x; x[14] = v.y; x[15] = v.z; x[16] = v.w; }
  };
  float x0[17], x1[17];
  load17(r0, x0);
  load17(r1, x1);

  // L1: 17 -> 16 (K odd: scalar fmaf, each weight used for BOTH rows)
  v2f h1v0[8], h1v1[8];
#pragma unroll
  for (int o = 0; o < 16; o++) {
    float s0 = lb1[o], s1 = s0;
#pragma unroll
    for (int i = 0; i < 17; i++) {
      const float w = lw1[o * 17 + i];
      s0 = fmaf(w, x0[i], s0);
      s1 = fmaf(w, x1[i], s1);
    }
    h1v0[o >> 1][o & 1] = fast_tanh(s0);
    h1v1[o >> 1][o & 1] = fast_tanh(s1);
  }
  // L2: 16 -> 32, K-packed; each weight s-pair feeds both rows' pk chains
  v2f h2v0[16], h2v1[16];
#pragma unroll
  for (int o = 0; o < 32; o++) {
    v2f a0 = {lb2[o], 0.0f};
    v2f a1 = a0;
    const v2f* w2 = (const v2f*)(lw2 + o * 16);
#pragma unroll
    for (int m = 0; m < 8; m++) {
      const v2f w = w2[m];
      a0 = pk_fma(w, h1v0[m], a0);
      a1 = pk_fma(w, h1v1[m], a1);
    }
    h2v0[o >> 1][o & 1] = fast_tanh(a0.x + a0.y);
    h2v1[o >> 1][o & 1] = fast_tanh(a1.x + a1.y);
  }
  // L3: 32 -> 16, K-packed; per-thread sum of the two rows -> LDS (stride 17)
#pragma unroll
  for (int o = 0; o < 16; o++) {
    v2f a0 = {lb3[o], 0.0f};
    v2f a1 = a0;
    const v2f* w3 = (const v2f*)(lw3 + o * 32);
#pragma unroll
    for (int m = 0; m < 16; m++) {
      const v2f w = w3[m];
      a0 = pk_fma(w, h2v0[m], a0);
      a1 = pk_fma(w, h2v1[m], a1);
    }
    const float t0 = fast_tanh(a0.x + a0.y);
    const float t1 = fast_tanh(a1.x + a1.y);
    red[tid * 17 + o] = (v0 ? t0 : 0.0f) + (v1 ? t1 : 0.0f);
  }
  __syncthreads();

  // stage 2: thread (g = tid>>4, c = tid&15) sums 16 rows of column c
  {
    const int c = tid & 15, g = tid >> 4;
    float part = 0.0f;
#pragma unroll
    for (int rr = 0; rr < 16; rr++) part += red[(g * 16 + rr) * 17 + c];
    red2[g * 17 + c] = part;
  }
  __syncthreads();
  if (tid < 16) {
    float s = 0.0f;
#pragma unroll
    for (int g = 0; g < 16; g++) s += red2[g * 17 + tid];
    atomicAdd(&acc_out[tid * 16], s);  // 64 B apart: one cache line per component
  }
}

// ---------- t-nets: single block, writes Tall[29] to ws ----------
struct CArgs {
  const float* w1[5]; const float* b1[5];
  const float* w2[5]; const float* b2[5];
  const float* w3[5]; const float* b3[5];
};

__global__ __launch_bounds__(256) void tnet_kernel(
    CArgs ta, const float* __restrict__ ws_acc, float* __restrict__ tall, int n) {
  const int tid = threadIdx.x;
  __shared__ float lat[16];
  __shared__ float H1s[5][48];
  __shared__ float H2s[5][32];

  if (tid < 16) lat[tid] = ws_acc[tid * 16] * (1.0f / (float)n);
  __syncthreads();
  if (tid < 240) {  // _tnet layer 1: 16 -> 48, tanh
    int net = tid / 48, o = tid % 48;
    float s = ta.b1[net][o];
#pragma unroll
    for (int i = 0; i < 16; i++) s = fmaf(ta.w1[net][o * 16 + i], lat[i], s);
    H1s[net][o] = fast_tanh(s);
  }
  __syncthreads();
  if (tid < 160) {  // _tnet layer 2: 48 -> 32, tanh
    int net = tid / 32, o = tid % 32;
    float s = ta.b2[net][o];
#pragma unroll
    for (int i = 0; i < 48; i++) s = fmaf(ta.w2[net][o * 48 + i], H1s[net][i], s);
    H2s[net][o] = fast_tanh(s);
  }
  __syncthreads();
  if (tid < 29) {   // _tnet layer 3: 32 -> dd*dd, + eye(dd)
    int net, o, dd;
    if      (tid < 4)  { net = 0; o = tid;      dd = 2; }
    else if (tid < 5)  { net = 1; o = tid - 4;  dd = 1; }
    else if (tid < 9)  { net = 2; o = tid - 5;  dd = 2; }
    else if (tid < 13) { net = 3; o = tid - 9;  dd = 2; }
    else               { net = 4; o = tid - 13; dd = 4; }
    float s = ta.b3[net][o];
#pragma unroll
    for (int i = 0; i < 32; i++) s = fmaf(ta.w3[net][o * 32 + i], H2s[net][i], s);
    if (o / dd == o % dd) s += 1.0f;
    tall[tid] = s;
  }
}

// ---------- phase C: pure streaming per-row transform + j-net (no LDS, no barriers) ----------
__global__ __launch_bounds__(TPB, 4) void phaseC_kernel(
    const float* __restrict__ tall,
    const float* __restrict__ cov,  const float* __restrict__ uu,
    const float* __restrict__ bnd,  const float* __restrict__ su,
    const float* __restrict__ sux,  const float* __restrict__ suxx,
    const float* __restrict__ spde,
    const float* __restrict__ jw1,  const float* __restrict__ jb1,
    const float* __restrict__ jw2,  const float* __restrict__ jb2,
    const float* __restrict__ jw3,  const float* __restrict__ jb3,
    const float* __restrict__ jw4,  const float* __restrict__ jb4,
    float* __restrict__ out, int n) {
  const int row = blockIdx.x * TPB + threadIdx.x;
  if (row >= n) return;

  // Tall[29]: wave-uniform -> scalar loads through K$ (do NOT copy into a VGPR array)
  // T(4)@0, Tu(1)@4, Tux(4)@5, Tuxx(4)@9, Tp(16)@13 (row-major dd x dd)

  // ---- literal t_params ----
  const float4 c4 = *(const float4*)(cov + (size_t)row * 4);
  float tp[15];
  // t_cov[i,k] = sum_j T[i,j] * cov[j,k]
  tp[0] = tall[0] * c4.x + tall[1] * c4.z;
  tp[1] = tall[0] * c4.y + tall[1] * c4.w;
  tp[2] = tall[2] * c4.x + tall[3] * c4.z;
  tp[3] = tall[2] * c4.y + tall[3] * c4.w;
  tp[4] = tall[4] * uu[row];          // t_u
  tp[5] = bnd[row];                   // b passthrough
  tp[6] = tall[4] * su[row];          // t_su
  { const float2 v = *(const float2*)(sux + (size_t)row * 2);
    tp[7] = tall[5] * v.x + tall[6] * v.y;
    tp[8] = tall[7] * v.x + tall[8] * v.y; }
  { const float2 v = *(const float2*)(suxx + (size_t)row * 2);
    tp[9]  = tall[9]  * v.x + tall[10] * v.y;
    tp[10] = tall[11] * v.x + tall[12] * v.y; }
  { const float4 v = *(const float4*)(spde + (size_t)row * 4);
#pragma unroll
    for (int a = 0; a < 4; a++)
      tp[11 + a] = tall[13 + a * 4] * v.x + tall[13 + a * 4 + 1] * v.y +
                   tall[13 + a * 4 + 2] * v.z + tall[13 + a * 4 + 3] * v.w; }

  // ---- j-net: 15 -> 16 -> 32 -> 48 -> 16 ----
  // L1 (K=15 odd: scalar fmaf), results into v2f pairs
  v2f a1v[8];
#pragma unroll
  for (int o = 0; o < 16; o++) {
    float s = jb1[o];
#pragma unroll
    for (int i = 0; i < 15; i++) s = fmaf(jw1[o * 15 + i], tp[i], s);
    a1v[o >> 1][o & 1] = fast_tanh(s);
  }
  // L2: 16 -> 32, packed
  v2f a2v[16];
#pragma unroll
  for (int o = 0; o < 32; o++) {
    v2f acc = {jb2[o], 0.0f};
    const v2f* w2 = (const v2f*)(jw2 + o * 16);
#pragma unroll
    for (int m = 0; m < 8; m++) acc = pk_fma(w2[m], a1v[m], acc);
    a2v[o >> 1][o & 1] = fast_tanh(acc.x + acc.y);
  }
  // L3+L4 streamed in o-PAIRS: dot(32) packed for o and o+1, tanh both, then
  // a4v[j] += {w4[j][o], w4[j][o+1]} * {h0, h1} (adjacent weights -> packed).
  // Never materializes g3[48]; peak live = a2v(32) + a4v(32) + 2 acc pairs.
  v2f a4v[16];
#pragma unroll
  for (int j = 0; j < 16; j++) { v2f t = {jb4[j], 0.0f}; a4v[j] = t; }
#pragma unroll 4
  for (int op = 0; op < 24; op++) {
    const int o0 = op * 2;
    v2f acc0 = {jb3[o0], 0.0f};
    v2f acc1 = {jb3[o0 + 1], 0.0f};
    const v2f* w30 = (const v2f*)(jw3 + o0 * 32);
    const v2f* w31 = (const v2f*)(jw3 + (o0 + 1) * 32);
#pragma unroll
    for (int m = 0; m < 16; m++) {
      acc0 = pk_fma(w30[m], a2v[m], acc0);
      acc1 = pk_fma(w31[m], a2v[m], acc1);
    }
    v2f h;
    h.x = fast_tanh(acc0.x + acc0.y);
    h.y = fast_tanh(acc1.x + acc1.y);
#pragma unroll
    for (int j = 0; j < 16; j++)
      a4v[j] = pk_fma(*(const v2f*)(jw4 + j * 48 + o0), h, a4v[j]);
  }
  float4* p = (float4*)(out + (size_t)row * 16);
  p[0] = make_float4(a4v[0].x + a4v[0].y,   a4v[1].x + a4v[1].y,
                     a4v[2].x + a4v[2].y,   a4v[3].x + a4v[3].y);
  p[1] = make_float4(a4v[4].x + a4v[4].y,   a4v[5].x + a4v[5].y,
                     a4v[6].x + a4v[6].y,   a4v[7].x + a4v[7].y);
  p[2] = make_float4(a4v[8].x + a4v[8].y,   a4v[9].x + a4v[9].y,
                     a4v[10].x + a4v[10].y, a4v[11].x + a4v[11].y);
  p[3] = make_float4(a4v[12].x + a4v[12].y, a4v[13].x + a4v[13].y,
                     a4v[14].x + a4v[14].y, a4v[15].x + a4v[15].y);
}

// ---------- launch ----------
extern "C" void kernel_launch(void* const* d_in, const int* in_sizes, int n_in,
                              void* d_out, int out_size, void* d_ws, size_t ws_size,
                              hipStream_t stream) {
  float* ws = (float*)d_ws;
  const int n = in_sizes[3];              // boundaries: (N,)
  const int nblkC = (n + TPB - 1) / TPB;
  const int nblkA = (n + 2 * TPB - 1) / (2 * TPB);

  zero_kernel<<<1, 256, 0, stream>>>(ws);

  phaseA_kernel<<<nblkA, TPB, 0, stream>>>(
      (const float*)d_in[0], (const float*)d_in[1], (const float*)d_in[2],
      (const float*)d_in[3], (const float*)d_in[4], (const float*)d_in[5],
      (const float*)d_in[6], (const float*)d_in[7],
      (const float*)d_in[8], (const float*)d_in[9], (const float*)d_in[10],
      (const float*)d_in[11], (const float*)d_in[12], (const float*)d_in[13],
      ws, n);

  CArgs ca;
  for (int k = 0; k < 5; k++) {
    int b = 14 + 6 * k;
    ca.w1[k] = (const float*)d_in[b];     ca.b1[k] = (const float*)d_in[b + 1];
    ca.w2[k] = (const float*)d_in[b + 2]; ca.b2[k] = (const float*)d_in[b + 3];
    ca.w3[k] = (const float*)d_in[b + 4]; ca.b3[k] = (const float*)d_in[b + 5];
  }

  tnet_kernel<<<1, 256, 0, stream>>>(ca, ws, ws + 256, n);

  phaseC_kernel<<<nblkC, TPB, 0, stream>>>(
      ws + 256,
      (const float*)d_in[1], (const float*)d_in[2], (const float*)d_in[3],
      (const float*)d_in[4], (const float*)d_in[5], (const float*)d_in[6],
      (const float*)d_in[7],
      (const float*)d_in[44], (const float*)d_in[45],
      (const float*)d_in[46], (const float*)d_in[47],
      (const float*)d_in[48], (const float*)d_in[49],
      (const float*)d_in[50], (const float*)d_in[51],
      (float*)d_out, n);
}